// Round 1
// 68723.157 us; speedup vs baseline: 2.9705x; 2.9705x over previous
//
#include <hip/hip_runtime.h>
#include <cstddef>

// Problem constants (fixed by reference)
#define BB   32
#define TT   2048
#define DIM  512
#define HH   1024
#define NBLK 256
#define NTHR 512

__device__ __forceinline__ float sigmoidf_(float x) {
    return 1.f / (1.f + __expf(-x));
}
__device__ __forceinline__ float tanhf_(float x) {
    float c = fminf(fmaxf(x, -15.f), 15.f);
    float e = __expf(2.f * c);
    return (e - 1.f) / (e + 1.f);
}

// Device-coherent (agent-scope, cache-bypassing) accesses for cross-block data.
// These compile to global_load/store with sc0/sc1 set: they are serviced at the
// coherence point (MALL), never emit buffer_inv/buffer_wbl2, and leave the
// weight working set undisturbed in L1/L2.
__device__ __forceinline__ float cload(const float* p) {
    return __hip_atomic_load(p, __ATOMIC_RELAXED, __HIP_MEMORY_SCOPE_AGENT);
}
__device__ __forceinline__ void cstore(float* p, float v) {
    __hip_atomic_store(p, v, __ATOMIC_RELAXED, __HIP_MEMORY_SCOPE_AGENT);
}

// ---------------- setup kernels ----------------

__global__ void k_init(const float* __restrict__ x0, float* __restrict__ xT,
                       float* __restrict__ ha, float* __restrict__ hb,
                       unsigned* __restrict__ bar) {
    int i = blockIdx.x * blockDim.x + threadIdx.x;
    if (i < DIM * BB) { int d = i >> 5, b = i & 31; xT[d * BB + b] = x0[b * DIM + d]; }
    if (i < HH * BB) { ha[i] = 0.f; hb[i] = 0.f; }
    if (i < 8192) bar[i] = 0u;   // flags[256*16] + release line
}

// Wc[i][d] = sum_k W_ih[i][k] * W_enc[k][d]   (i<3072, d<512, k<1024)
__global__ void k_wc(const float* __restrict__ Wih, const float* __restrict__ Wenc,
                     float* __restrict__ Wc) {
    int db = blockIdx.x & 7, ib = blockIdx.x >> 3;
    int d = db * 64 + (threadIdx.x & 63);
    int i = ib * 4 + (threadIdx.x >> 6);
    const float4* wi4 = (const float4*)(Wih + (size_t)i * HH);
    float acc = 0.f;
    for (int k4 = 0; k4 < HH / 4; ++k4) {
        float4 w = wi4[k4];
        int k = k4 * 4;
        acc += w.x * Wenc[(size_t)(k + 0) * DIM + d];
        acc += w.y * Wenc[(size_t)(k + 1) * DIM + d];
        acc += w.z * Wenc[(size_t)(k + 2) * DIM + d];
        acc += w.w * Wenc[(size_t)(k + 3) * DIM + d];
    }
    Wc[(size_t)i * DIM + d] = acc;
}

// bc[i] = sum_k W_ih[i][k] * b_enc[k] + b_gru[i]
__global__ void k_bc(const float* __restrict__ Wih, const float* __restrict__ benc,
                     const float* __restrict__ bgru, float* __restrict__ bc) {
    int i = blockIdx.x;
    float s = 0.f;
    for (int k = threadIdx.x; k < HH; k += 256) s += Wih[(size_t)i * HH + k] * benc[k];
    __shared__ float red[256];
    red[threadIdx.x] = s; __syncthreads();
    for (int off = 128; off > 0; off >>= 1) {
        if (threadIdx.x < off) red[threadIdx.x] += red[threadIdx.x + off];
        __syncthreads();
    }
    if (threadIdx.x == 0) bc[i] = red[0] + bgru[i];
}

// ---------------- fence-free grid barrier ----------------
// Per-block epoch flags on distinct cachelines; block 0 polls, then releases.
// All flag traffic is relaxed agent-scope (sc0/sc1) -> NO cache invalidates.
// Data visibility: all cross-block data ops are themselves agent-coherent, and
// every wave drains vmcnt(0) at __syncthreads before its flag is set.
__device__ __forceinline__ void gbar(unsigned* flags, unsigned* rel, unsigned* pe) {
    const unsigned e = ++(*pe);
    asm volatile("" ::: "memory");
    __syncthreads();                       // all waves' coherent stores drained
    if (blockIdx.x == 0) {
        if (threadIdx.x < 64) {
            for (int i = 1 + (int)threadIdx.x; i < NBLK; i += 64) {
                while (__hip_atomic_load(&flags[i << 4], __ATOMIC_RELAXED,
                                         __HIP_MEMORY_SCOPE_AGENT) < e)
                    __builtin_amdgcn_s_sleep(1);
            }
        }
        __syncthreads();
        if (threadIdx.x == 0)
            __hip_atomic_store(rel, e, __ATOMIC_RELAXED, __HIP_MEMORY_SCOPE_AGENT);
    } else {
        if (threadIdx.x == 0) {
            __hip_atomic_store(&flags[blockIdx.x << 4], e, __ATOMIC_RELAXED,
                               __HIP_MEMORY_SCOPE_AGENT);
            while (__hip_atomic_load(rel, __ATOMIC_RELAXED,
                                     __HIP_MEMORY_SCOPE_AGENT) < e)
                __builtin_amdgcn_s_sleep(1);
        }
        __syncthreads();
    }
    asm volatile("" ::: "memory");
}

// ---------------- persistent recurrent kernel ----------------
// 512 threads: tid = v*32 + b, v in [0,16) is the K-chunk, b is the batch lane.
// Phase A: each thread accumulates 4 GRU rows (jj=0..3) over its K-chunk
//          (x: 32 elems, h: 64 elems) -> each coherent x/h value is loaded once
//          and reused for 12 weight rows (weights are plain cached loads).
// Phase B: each thread accumulates 4 decoder rows (mu/ls x 2 cols) over a
//          64-elem chunk of h_new.
__global__ void __launch_bounds__(NTHR) k_gru(
    const float* __restrict__ Wc, const float* __restrict__ bc,
    const float* __restrict__ Whh, const float* __restrict__ Wdec,
    const float* __restrict__ bn, const float* __restrict__ bdec,
    const float* __restrict__ eps, float* __restrict__ xT,
    float* __restrict__ ha, float* __restrict__ hb,
    float* __restrict__ out, unsigned* __restrict__ bar)
{
    const int tid = threadIdx.x;
    const int b = tid & 31;
    const int v = tid >> 5;               // 0..15
    const int blk = blockIdx.x;

    __shared__ float sm[16 * 4 * 32 * 5];   // 40 KB, pad-5 -> conflict-free
    #define EXA(vv, jj, bb, c) sm[((((vv) * 4 + (jj)) * 32 + (bb)) * 5) + (c)]
    #define EXB(kv, bb, r)     sm[(((kv) * 32 + (bb)) * 5) + (r)]

    unsigned* flags = bar;
    unsigned* rel = bar + 4096;
    unsigned epoch = 0;

    // ---- phase A bases ----
    const int j0 = blk << 2;                               // rows j0..j0+3
    const float* pc = Wc + (size_t)j0 * DIM + v * 32;
    const float* ph = Whh + (size_t)j0 * HH + v * 64;

    // finalize-A constants (tid<128: jj = tid>>5)
    float bcr = 0.f, bcz = 0.f, bcn = 0.f, bnj = 0.f;
    if (tid < 128) {
        int j = j0 + (tid >> 5);
        bcr = bc[j]; bcz = bc[j + HH]; bcn = bc[j + 2 * HH]; bnj = bn[j];
    }

    // ---- phase B bases: XCD-swizzled column pair so the 8 blocks sharing an
    // eps/out cacheline live on the same XCD (blk%8 = XCD round-robin) ----
    const int p_ = ((blk & 7) << 5) + (blk >> 3);          // 0..255, bijective
    const int dcol0 = p_ << 1;
    const float* pd = Wdec + (size_t)dcol0 * HH + v * 64;
    float bd0 = 0.f, bd1 = 0.f;
    if (tid < 64) {
        int dcol = dcol0 + (tid >> 5);
        bd0 = bdec[dcol]; bd1 = bdec[dcol + DIM];
    }

    const size_t TBD = (size_t)TT * BB * DIM;

    for (int t = 0; t < TT; ++t) {
        const float* hcur = (t & 1) ? hb : ha;
        float* hnew = (t & 1) ? ha : hb;

        // prefetch eps (plain cached; line shared by 8 co-XCD blocks) and h_old
        float ev = 0.f; size_t o = 0;
        if (tid < 64) {
            o = ((size_t)t * BB + b) * DIM + (dcol0 + (tid >> 5));
            ev = eps[o];
        }
        float hold = 0.f;
        if (tid < 128) hold = cload(&hcur[(size_t)(j0 + (tid >> 5)) * BB + b]);

        // ================= phase A: gates -> h_new =================
        {
            float ar[4] = {0, 0, 0, 0}, az[4] = {0, 0, 0, 0};
            float an[4] = {0, 0, 0, 0}, ap[4] = {0, 0, 0, 0};
            #pragma unroll 4
            for (int u = 0; u < 8; ++u) {                  // x chunk: 32 elems
                const int k = v * 32 + u * 4;
                float x0v = cload(&xT[(k + 0) * BB + b]);
                float x1v = cload(&xT[(k + 1) * BB + b]);
                float x2v = cload(&xT[(k + 2) * BB + b]);
                float x3v = cload(&xT[(k + 3) * BB + b]);
                #pragma unroll
                for (int jj = 0; jj < 4; ++jj) {
                    const float* base = pc + (size_t)jj * DIM + u * 4;
                    float4 wr = *(const float4*)(base);
                    float4 wz = *(const float4*)(base + (size_t)HH * DIM);
                    float4 wn = *(const float4*)(base + (size_t)2 * HH * DIM);
                    ar[jj] += wr.x * x0v + wr.y * x1v + wr.z * x2v + wr.w * x3v;
                    az[jj] += wz.x * x0v + wz.y * x1v + wz.z * x2v + wz.w * x3v;
                    an[jj] += wn.x * x0v + wn.y * x1v + wn.z * x2v + wn.w * x3v;
                }
            }
            #pragma unroll 4
            for (int u = 0; u < 16; ++u) {                 // h chunk: 64 elems
                const int k = v * 64 + u * 4;
                float h0v = cload(&hcur[(k + 0) * BB + b]);
                float h1v = cload(&hcur[(k + 1) * BB + b]);
                float h2v = cload(&hcur[(k + 2) * BB + b]);
                float h3v = cload(&hcur[(k + 3) * BB + b]);
                #pragma unroll
                for (int jj = 0; jj < 4; ++jj) {
                    const float* base = ph + (size_t)jj * HH + u * 4;
                    float4 ur = *(const float4*)(base);
                    float4 uz = *(const float4*)(base + (size_t)HH * HH);
                    float4 un = *(const float4*)(base + (size_t)2 * HH * HH);
                    ar[jj] += ur.x * h0v + ur.y * h1v + ur.z * h2v + ur.w * h3v;
                    az[jj] += uz.x * h0v + uz.y * h1v + uz.z * h2v + uz.w * h3v;
                    ap[jj] += un.x * h0v + un.y * h1v + un.z * h2v + un.w * h3v;
                }
            }
            #pragma unroll
            for (int jj = 0; jj < 4; ++jj) {
                float* e = &EXA(v, jj, b, 0);
                e[0] = ar[jj]; e[1] = az[jj]; e[2] = an[jj]; e[3] = ap[jj];
            }
            __syncthreads();
            if (tid < 128) {
                const int jj = tid >> 5;
                float sr = 0.f, sz = 0.f, sn = 0.f, sp = 0.f;
                #pragma unroll
                for (int vv = 0; vv < 16; ++vv) {
                    const float* e = &EXA(vv, jj, b, 0);
                    sr += e[0]; sz += e[1]; sn += e[2]; sp += e[3];
                }
                float r = sigmoidf_(sr + bcr);
                float z = sigmoidf_(sz + bcz);
                float n = tanhf_(sn + bcn + r * (sp + bnj));
                cstore(&hnew[(size_t)(j0 + jj) * BB + b], n + z * (hold - n));
            }
        }
        gbar(flags, rel, &epoch);

        // ================= phase B: decoder -> outputs + x_next =================
        {
            float a0 = 0.f, a1 = 0.f, a2 = 0.f, a3 = 0.f;  // mu d0, mu d1, ls d0, ls d1
            #pragma unroll 4
            for (int u = 0; u < 16; ++u) {                 // h chunk: 64 elems
                const int k = v * 64 + u * 4;
                float h0v = cload(&hnew[(k + 0) * BB + b]);
                float h1v = cload(&hnew[(k + 1) * BB + b]);
                float h2v = cload(&hnew[(k + 2) * BB + b]);
                float h3v = cload(&hnew[(k + 3) * BB + b]);
                const float* base = pd + u * 4;
                float4 w0 = *(const float4*)(base);
                float4 w1 = *(const float4*)(base + HH);
                float4 w2 = *(const float4*)(base + (size_t)DIM * HH);
                float4 w3 = *(const float4*)(base + (size_t)(DIM + 1) * HH);
                a0 += w0.x * h0v + w0.y * h1v + w0.z * h2v + w0.w * h3v;
                a1 += w1.x * h0v + w1.y * h1v + w1.z * h2v + w1.w * h3v;
                a2 += w2.x * h0v + w2.y * h1v + w2.z * h2v + w2.w * h3v;
                a3 += w3.x * h0v + w3.y * h1v + w3.z * h2v + w3.w * h3v;
            }
            {
                float* e = &EXB(v, b, 0);
                e[0] = a0; e[1] = a1; e[2] = a2; e[3] = a3;
            }
            __syncthreads();
            if (tid < 64) {
                const int dd = tid >> 5;
                float mu = 0.f, ls = 0.f;
                #pragma unroll
                for (int kv = 0; kv < 16; ++kv) {
                    const float* q = &EXB(kv, b, 0);
                    mu += q[dd]; ls += q[2 + dd];
                }
                mu += bd0; ls += bd1;
                float sg = __expf(ls);
                float xn = mu + sg * ev;
                __builtin_nontemporal_store(xn, &out[o]);
                __builtin_nontemporal_store(mu, &out[TBD + o]);
                __builtin_nontemporal_store(sg, &out[2 * TBD + o]);
                cstore(&xT[(size_t)(dcol0 + dd) * BB + b], xn);
            }
        }
        gbar(flags, rel, &epoch);
    }
    #undef EXA
    #undef EXB
}

// ---------------- launch ----------------

extern "C" void kernel_launch(void* const* d_in, const int* in_sizes, int n_in,
                              void* d_out, int out_size, void* d_ws, size_t ws_size,
                              hipStream_t stream) {
    const float* x0   = (const float*)d_in[0];
    const float* eps  = (const float*)d_in[1];
    const float* Wenc = (const float*)d_in[2];
    const float* benc = (const float*)d_in[3];
    const float* Wih  = (const float*)d_in[4];
    const float* Whh  = (const float*)d_in[5];
    const float* bgru = (const float*)d_in[6];
    const float* bn   = (const float*)d_in[7];
    const float* Wdec = (const float*)d_in[8];
    const float* bdec = (const float*)d_in[9];
    float* out = (float*)d_out;

    // workspace layout (floats): Wc | bc | xT | ha | hb | bar (8192 u32)
    float* ws = (float*)d_ws;
    float* Wc = ws;
    float* bc = Wc + (size_t)3 * HH * DIM;   // 1,572,864
    float* xT = bc + 3 * HH;                 // + 3072
    float* ha = xT + DIM * BB;               // + 16384
    float* hb = ha + HH * BB;                // + 32768
    unsigned* bar = (unsigned*)(hb + HH * BB);

    hipLaunchKernelGGL(k_init, dim3(128), dim3(256), 0, stream, x0, xT, ha, hb, bar);
    hipLaunchKernelGGL(k_wc, dim3(6144), dim3(256), 0, stream, Wih, Wenc, Wc);
    hipLaunchKernelGGL(k_bc, dim3(3072), dim3(256), 0, stream, Wih, benc, bgru, bc);

    void* args[] = { &Wc, &bc, (void*)&Whh, (void*)&Wdec, (void*)&bn, (void*)&bdec,
                     (void*)&eps, &xT, &ha, &hb, &out, &bar };
    hipLaunchCooperativeKernel((void*)k_gru, dim3(NBLK), dim3(NTHR), args, 0, stream);
}